// Round 1
// baseline (3350.726 us; speedup 1.0000x reference)
//
#include <hip/hip_runtime.h>
#include <hip/hip_bf16.h>

#define EPSV 0.2f
#define USER_NUM 100000
#define ITEM_NUM 50000
#define NTOT (USER_NUM + ITEM_NUM)
#define NNZ_CNT 1200000
#define EMB 64

// Scatter SpMM: ego_new[r] += vals[e] * ego_old[c] for each edge e=(r,c).
// 16 lanes per edge, each lane handles a float4 (16B) slice of the 64-elem row.
__global__ void scatter_kernel(const float* __restrict__ ego_old,
                               const int* __restrict__ rows,
                               const int* __restrict__ cols,
                               const float* __restrict__ vals,
                               float* __restrict__ ego_new) {
    int g = blockIdx.x * blockDim.x + threadIdx.x;
    int e = g >> 4;
    int sub = g & 15;
    if (e >= NNZ_CNT) return;
    int r = rows[e];
    int c = cols[e];
    float v = vals[e];
    const float4* src = (const float4*)(ego_old + (size_t)c * EMB);
    float4 x = src[sub];
    float* dst = ego_new + (size_t)r * EMB + sub * 4;
    atomicAdd(dst + 0, v * x.x);
    atomicAdd(dst + 1, v * x.y);
    atomicAdd(dst + 2, v * x.z);
    atomicAdd(dst + 3, v * x.w);
}

// Per-row: y = x + sign(x) * (noise_row / max(||noise_row||,1e-12)) * EPS
// in-place on ego; final += y/3 (or = y/3 on first layer); cl = y if write_cl.
// One 64-lane wave per row; 4 rows per 256-thread block.
__global__ void perturb_kernel(float* __restrict__ ego,
                               const float* __restrict__ noise_k,
                               float* __restrict__ final_out,
                               float* __restrict__ cl_out,
                               int write_cl, int first_layer) {
    int row = blockIdx.x * 4 + (threadIdx.x >> 6);
    int lane = threadIdx.x & 63;
    if (row >= NTOT) return;
    size_t idx = (size_t)row * EMB + lane;
    float nv = noise_k[idx];
    float s = nv * nv;
    // wave64 butterfly reduction
    #pragma unroll
    for (int off = 32; off > 0; off >>= 1) s += __shfl_xor(s, off, 64);
    float norm = sqrtf(s);
    float nn = nv / fmaxf(norm, 1e-12f);
    float x = ego[idx];
    float sg = (x > 0.f) ? 1.f : ((x < 0.f) ? -1.f : 0.f);
    float y = x + sg * nn * EPSV;
    ego[idx] = y;
    const float third = 1.f / 3.f;
    if (first_layer) final_out[idx] = y * third;
    else             final_out[idx] += y * third;
    if (write_cl) cl_out[idx] = y;
}

extern "C" void kernel_launch(void* const* d_in, const int* in_sizes, int n_in,
                              void* d_out, int out_size, void* d_ws, size_t ws_size,
                              hipStream_t stream) {
    const float* user_emb = (const float*)d_in[0];
    const float* item_emb = (const float*)d_in[1];
    const int*   adj_rows = (const int*)d_in[2];
    const int*   adj_cols = (const int*)d_in[3];
    const float* adj_vals = (const float*)d_in[4];
    const float* noise    = (const float*)d_in[5];

    float* out_final = (float*)d_out;                       // N x 64
    float* out_cl    = (float*)d_out + (size_t)NTOT * EMB;  // N x 64

    float* bufA = (float*)d_ws;                             // N x 64
    float* bufB = bufA + (size_t)NTOT * EMB;                // N x 64

    const size_t ego_bytes = (size_t)NTOT * EMB * sizeof(float);

    // ego0 = concat(user_emb, item_emb) -> bufA
    hipMemcpyAsync(bufA, user_emb, (size_t)USER_NUM * EMB * sizeof(float),
                   hipMemcpyDeviceToDevice, stream);
    hipMemcpyAsync(bufA + (size_t)USER_NUM * EMB, item_emb,
                   (size_t)ITEM_NUM * EMB * sizeof(float),
                   hipMemcpyDeviceToDevice, stream);

    const int scatter_threads = NNZ_CNT * 16;
    const int scatter_blocks = (scatter_threads + 255) / 256;
    const int perturb_blocks = (NTOT + 3) / 4;

    float* src = bufA;
    float* dst = bufB;
    for (int k = 0; k < 3; ++k) {
        hipMemsetAsync(dst, 0, ego_bytes, stream);
        scatter_kernel<<<scatter_blocks, 256, 0, stream>>>(
            src, adj_rows, adj_cols, adj_vals, dst);
        perturb_kernel<<<perturb_blocks, 256, 0, stream>>>(
            dst, noise + (size_t)k * NTOT * EMB, out_final, out_cl,
            /*write_cl=*/(k == 0) ? 1 : 0, /*first_layer=*/(k == 0) ? 1 : 0);
        float* t = src; src = dst; dst = t;
    }
}

// Round 2
// 587.283 us; speedup vs baseline: 5.7055x; 5.7055x over previous
//
#include <hip/hip_runtime.h>
#include <hip/hip_bf16.h>

#define EPSV 0.2f
#define USER_NUM 100000
#define ITEM_NUM 50000
#define NTOT 150000
#define NNZ_CNT 1200000
#define EMB 64
#define SCAN_BS 256
#define NBLK ((NTOT + SCAN_BS - 1) / SCAN_BS)   // 586

// ---- CSR build ----

__global__ void hist_kernel(const int* __restrict__ rows, int* __restrict__ hist) {
    int e = blockIdx.x * blockDim.x + threadIdx.x;
    if (e < NNZ_CNT) atomicAdd(&hist[rows[e]], 1);
}

__global__ void scan_local_kernel(const int* __restrict__ hist,
                                  int* __restrict__ rowstart,
                                  int* __restrict__ blocksum) {
    __shared__ int s[SCAN_BS];
    int t = threadIdx.x;
    int i = blockIdx.x * SCAN_BS + t;
    int v = (i < NTOT) ? hist[i] : 0;
    s[t] = v;
    __syncthreads();
    for (int off = 1; off < SCAN_BS; off <<= 1) {
        int x = (t >= off) ? s[t - off] : 0;
        __syncthreads();
        s[t] += x;
        __syncthreads();
    }
    if (i < NTOT) rowstart[i] = s[t] - v;  // block-local exclusive
    if (t == SCAN_BS - 1) blocksum[blockIdx.x] = s[t];
}

__global__ void scan_block_kernel(int* __restrict__ blocksum) {
    __shared__ int s[1024];
    int t = threadIdx.x;
    int v = (t < NBLK) ? blocksum[t] : 0;
    s[t] = v;
    __syncthreads();
    for (int off = 1; off < 1024; off <<= 1) {
        int x = (t >= off) ? s[t - off] : 0;
        __syncthreads();
        s[t] += x;
        __syncthreads();
    }
    if (t < NBLK) blocksum[t] = s[t] - v;  // exclusive
}

__global__ void scan_add_kernel(int* __restrict__ rowstart,
                                const int* __restrict__ blockoff) {
    int i = blockIdx.x * blockDim.x + threadIdx.x;
    if (i < NTOT) rowstart[i] += blockoff[i / SCAN_BS];
    if (i == 0) rowstart[NTOT] = NNZ_CNT;
}

__global__ void build_kernel(const int* __restrict__ rows,
                             const int* __restrict__ cols,
                             const float* __restrict__ vals,
                             const int* __restrict__ rowstart,
                             int* __restrict__ cnt2,
                             int* __restrict__ csr_col,
                             float* __restrict__ csr_val) {
    int e = blockIdx.x * blockDim.x + threadIdx.x;
    if (e >= NNZ_CNT) return;
    int r = rows[e];
    int slot = rowstart[r] + atomicAdd(&cnt2[r], 1);
    csr_col[slot] = cols[e];
    csr_val[slot] = vals[e];
}

// ---- Gather SpMM fused with perturbation / accumulation ----
// One 64-lane wave per row (lane = emb index), 4 rows per 256-thread block.
__global__ void spmm_perturb_kernel(const float* __restrict__ src,
                                    const int* __restrict__ rowstart,
                                    const int* __restrict__ csr_col,
                                    const float* __restrict__ csr_val,
                                    const float* __restrict__ noise_k,
                                    float* __restrict__ ego_out,
                                    float* __restrict__ final_out,
                                    int store_ego, int first_layer) {
    int row = blockIdx.x * 4 + (threadIdx.x >> 6);
    row = __builtin_amdgcn_readfirstlane(row);  // force wave-uniform -> scalar loads
    if (row >= NTOT) return;
    int lane = threadIdx.x & 63;
    int beg = rowstart[row];
    int end = rowstart[row + 1];
    float acc = 0.f;
    int j = beg;
    for (; j + 4 <= end; j += 4) {
        int c0 = csr_col[j];
        int c1 = csr_col[j + 1];
        int c2 = csr_col[j + 2];
        int c3 = csr_col[j + 3];
        float v0 = csr_val[j];
        float v1 = csr_val[j + 1];
        float v2 = csr_val[j + 2];
        float v3 = csr_val[j + 3];
        float x0 = src[(size_t)c0 * EMB + lane];
        float x1 = src[(size_t)c1 * EMB + lane];
        float x2 = src[(size_t)c2 * EMB + lane];
        float x3 = src[(size_t)c3 * EMB + lane];
        acc = fmaf(v0, x0, acc);
        acc = fmaf(v1, x1, acc);
        acc = fmaf(v2, x2, acc);
        acc = fmaf(v3, x3, acc);
    }
    for (; j < end; ++j) {
        acc = fmaf(csr_val[j], src[(size_t)csr_col[j] * EMB + lane], acc);
    }
    size_t idx = (size_t)row * EMB + lane;
    float nv = noise_k[idx];
    float s = nv * nv;
    #pragma unroll
    for (int off = 32; off > 0; off >>= 1) s += __shfl_xor(s, off, 64);
    float nn = nv / fmaxf(sqrtf(s), 1e-12f);
    float sg = (acc > 0.f) ? 1.f : ((acc < 0.f) ? -1.f : 0.f);
    float y = acc + sg * nn * EPSV;
    if (store_ego) ego_out[idx] = y;
    const float third = 1.f / 3.f;
    if (first_layer) final_out[idx] = y * third;
    else             final_out[idx] += y * third;
}

extern "C" void kernel_launch(void* const* d_in, const int* in_sizes, int n_in,
                              void* d_out, int out_size, void* d_ws, size_t ws_size,
                              hipStream_t stream) {
    const float* user_emb = (const float*)d_in[0];
    const float* item_emb = (const float*)d_in[1];
    const int*   adj_rows = (const int*)d_in[2];
    const int*   adj_cols = (const int*)d_in[3];
    const float* adj_vals = (const float*)d_in[4];
    const float* noise    = (const float*)d_in[5];

    float* out_final = (float*)d_out;                       // N x 64
    float* out_cl    = (float*)d_out + (size_t)NTOT * EMB;  // N x 64  (== ego after layer 0)

    // ws layout
    char* p = (char*)d_ws;
    float* wsA      = (float*)p;                    p += (size_t)NTOT * EMB * sizeof(float); // 38.4 MB
    int*   rowstart = (int*)p;                      p += (size_t)(NTOT + 16) * sizeof(int);
    int*   csr_col  = (int*)p;                      p += (size_t)NNZ_CNT * sizeof(int);
    float* csr_val  = (float*)p;                    p += (size_t)NNZ_CNT * sizeof(float);
    int*   hist     = (int*)p;                      p += (size_t)NTOT * sizeof(int);
    int*   cnt2     = (int*)p;                      p += (size_t)NTOT * sizeof(int);
    int*   blocksum = (int*)p;                      p += 1024 * sizeof(int);

    // zero the counters
    hipMemsetAsync(hist, 0, (size_t)NTOT * sizeof(int), stream);
    hipMemsetAsync(cnt2, 0, (size_t)NTOT * sizeof(int), stream);

    // ego0 = concat(user_emb, item_emb) -> wsA
    hipMemcpyAsync(wsA, user_emb, (size_t)USER_NUM * EMB * sizeof(float),
                   hipMemcpyDeviceToDevice, stream);
    hipMemcpyAsync(wsA + (size_t)USER_NUM * EMB, item_emb,
                   (size_t)ITEM_NUM * EMB * sizeof(float),
                   hipMemcpyDeviceToDevice, stream);

    // CSR build
    hist_kernel<<<(NNZ_CNT + 255) / 256, 256, 0, stream>>>(adj_rows, hist);
    scan_local_kernel<<<NBLK, SCAN_BS, 0, stream>>>(hist, rowstart, blocksum);
    scan_block_kernel<<<1, 1024, 0, stream>>>(blocksum);
    scan_add_kernel<<<(NTOT + 255) / 256, 256, 0, stream>>>(rowstart, blocksum);
    build_kernel<<<(NNZ_CNT + 255) / 256, 256, 0, stream>>>(
        adj_rows, adj_cols, adj_vals, rowstart, cnt2, csr_col, csr_val);

    const int spmm_blocks = (NTOT + 3) / 4;
    const size_t NE = (size_t)NTOT * EMB;

    // layer 0: src=wsA -> ego written to out_cl (cl == ego1); final = y/3
    spmm_perturb_kernel<<<spmm_blocks, 256, 0, stream>>>(
        wsA, rowstart, csr_col, csr_val, noise + 0 * NE,
        out_cl, out_final, /*store_ego=*/1, /*first_layer=*/1);
    // layer 1: src=out_cl -> ego to wsA (ego0 dead); final += y/3
    spmm_perturb_kernel<<<spmm_blocks, 256, 0, stream>>>(
        out_cl, rowstart, csr_col, csr_val, noise + 1 * NE,
        wsA, out_final, /*store_ego=*/1, /*first_layer=*/0);
    // layer 2: src=wsA -> ego not needed; final += y/3
    spmm_perturb_kernel<<<spmm_blocks, 256, 0, stream>>>(
        wsA, rowstart, csr_col, csr_val, noise + 2 * NE,
        nullptr, out_final, /*store_ego=*/0, /*first_layer=*/0);
}

// Round 3
// 493.205 us; speedup vs baseline: 6.7938x; 1.1907x over previous
//
#include <hip/hip_runtime.h>
#include <hip/hip_bf16.h>

#define EPSV 0.2f
#define USER_NUM 100000
#define ITEM_NUM 50000
#define NTOT 150000
#define NNZ_CNT 1200000
#define EMB 64
#define SCAN_BS 256
#define NBLK ((NTOT + SCAN_BS - 1) / SCAN_BS)   // 586

// ---- CSR build ----

// hist + ticket in one pass: ticket[e] = order of edge e within its row.
__global__ void hist_kernel(const int* __restrict__ rows,
                            int* __restrict__ hist,
                            int* __restrict__ ticket) {
    int e = blockIdx.x * blockDim.x + threadIdx.x;
    if (e < NNZ_CNT) ticket[e] = atomicAdd(&hist[rows[e]], 1);
}

__global__ void scan_local_kernel(const int* __restrict__ hist,
                                  int* __restrict__ rowstart,
                                  int* __restrict__ blocksum) {
    __shared__ int s[SCAN_BS];
    int t = threadIdx.x;
    int i = blockIdx.x * SCAN_BS + t;
    int v = (i < NTOT) ? hist[i] : 0;
    s[t] = v;
    __syncthreads();
    for (int off = 1; off < SCAN_BS; off <<= 1) {
        int x = (t >= off) ? s[t - off] : 0;
        __syncthreads();
        s[t] += x;
        __syncthreads();
    }
    if (i < NTOT) rowstart[i] = s[t] - v;  // block-local exclusive
    if (t == SCAN_BS - 1) blocksum[blockIdx.x] = s[t];
}

__global__ void scan_block_kernel(int* __restrict__ blocksum) {
    __shared__ int s[1024];
    int t = threadIdx.x;
    int v = (t < NBLK) ? blocksum[t] : 0;
    s[t] = v;
    __syncthreads();
    for (int off = 1; off < 1024; off <<= 1) {
        int x = (t >= off) ? s[t - off] : 0;
        __syncthreads();
        s[t] += x;
        __syncthreads();
    }
    if (t < NBLK) blocksum[t] = s[t] - v;  // exclusive
}

__global__ void scan_add_kernel(int* __restrict__ rowstart,
                                const int* __restrict__ blockoff) {
    int i = blockIdx.x * blockDim.x + threadIdx.x;
    if (i < NTOT) rowstart[i] += blockoff[i / SCAN_BS];
    if (i == 0) rowstart[NTOT] = NNZ_CNT;
}

// Packed scatter: one 8B store per edge instead of two 4B stores.
__global__ void build_kernel(const int* __restrict__ rows,
                             const int* __restrict__ cols,
                             const float* __restrict__ vals,
                             const int* __restrict__ rowstart,
                             const int* __restrict__ ticket,
                             int2* __restrict__ csr) {
    int e = blockIdx.x * blockDim.x + threadIdx.x;
    if (e >= NNZ_CNT) return;
    int r = rows[e];
    int slot = rowstart[r] + ticket[e];
    csr[slot] = make_int2(cols[e], __float_as_int(vals[e]));
}

// ---- Gather SpMM fused with perturbation / accumulation ----
// One 64-lane wave per row (lane = emb index), 4 rows per 256-thread block.
// 8-wide batched edge loop: 8 independent edge loads -> 8 independent 256B
// gathers -> 8 fmas; tail handled by clamping index + zeroing val.
template <bool CONCAT>
__global__ void spmm_perturb_kernel(const float* __restrict__ src,
                                    const float* __restrict__ user_emb,
                                    const float* __restrict__ item_emb,
                                    const int* __restrict__ rowstart,
                                    const int2* __restrict__ csr,
                                    const float* __restrict__ noise_k,
                                    float* __restrict__ ego_out,
                                    float* __restrict__ final_out,
                                    int store_ego, int first_layer) {
    int row = blockIdx.x * 4 + (threadIdx.x >> 6);
    row = __builtin_amdgcn_readfirstlane(row);  // wave-uniform -> scalar loads
    if (row >= NTOT) return;
    int lane = threadIdx.x & 63;
    size_t idx = (size_t)row * EMB + lane;
    float nv = noise_k[idx];          // issue early; used after the loop
    int beg = rowstart[row];
    int end = rowstart[row + 1];
    float acc = 0.f;
    for (int j = beg; j < end; j += 8) {
        int   cb[8];
        float vb[8];
        #pragma unroll
        for (int u = 0; u < 8; ++u) {
            int jj = j + u;
            int2 ee = csr[(jj < end) ? jj : (end - 1)];
            cb[u] = ee.x;
            vb[u] = (jj < end) ? __int_as_float(ee.y) : 0.f;
        }
        float xb[8];
        #pragma unroll
        for (int u = 0; u < 8; ++u) {
            int c = cb[u];
            const float* base;
            if (CONCAT)
                base = (c < USER_NUM) ? (user_emb + (size_t)c * EMB)
                                      : (item_emb + (size_t)(c - USER_NUM) * EMB);
            else
                base = src + (size_t)c * EMB;
            xb[u] = base[lane];
        }
        #pragma unroll
        for (int u = 0; u < 8; ++u) acc = fmaf(vb[u], xb[u], acc);
    }
    float s = nv * nv;
    #pragma unroll
    for (int off = 32; off > 0; off >>= 1) s += __shfl_xor(s, off, 64);
    float nn = nv / fmaxf(sqrtf(s), 1e-12f);
    float sg = (acc > 0.f) ? 1.f : ((acc < 0.f) ? -1.f : 0.f);
    float y = acc + sg * nn * EPSV;
    if (store_ego) ego_out[idx] = y;
    const float third = 1.f / 3.f;
    if (first_layer) final_out[idx] = y * third;
    else             final_out[idx] += y * third;
}

extern "C" void kernel_launch(void* const* d_in, const int* in_sizes, int n_in,
                              void* d_out, int out_size, void* d_ws, size_t ws_size,
                              hipStream_t stream) {
    const float* user_emb = (const float*)d_in[0];
    const float* item_emb = (const float*)d_in[1];
    const int*   adj_rows = (const int*)d_in[2];
    const int*   adj_cols = (const int*)d_in[3];
    const float* adj_vals = (const float*)d_in[4];
    const float* noise    = (const float*)d_in[5];

    float* out_final = (float*)d_out;                       // N x 64
    float* out_cl    = (float*)d_out + (size_t)NTOT * EMB;  // N x 64  (== ego after layer 0)

    // ws layout
    char* p = (char*)d_ws;
    float* wsA      = (float*)p;  p += (size_t)NTOT * EMB * sizeof(float); // 38.4 MB
    int*   rowstart = (int*)p;    p += (size_t)(NTOT + 16) * sizeof(int);
    int2*  csr      = (int2*)p;   p += (size_t)NNZ_CNT * sizeof(int2);     // 9.6 MB
    int*   hist     = (int*)p;    p += (size_t)NTOT * sizeof(int);
    int*   ticket   = (int*)p;    p += (size_t)NNZ_CNT * sizeof(int);      // 4.8 MB
    int*   blocksum = (int*)p;    p += 1024 * sizeof(int);

    hipMemsetAsync(hist, 0, (size_t)NTOT * sizeof(int), stream);

    // CSR build
    hist_kernel<<<(NNZ_CNT + 255) / 256, 256, 0, stream>>>(adj_rows, hist, ticket);
    scan_local_kernel<<<NBLK, SCAN_BS, 0, stream>>>(hist, rowstart, blocksum);
    scan_block_kernel<<<1, 1024, 0, stream>>>(blocksum);
    scan_add_kernel<<<(NTOT + 255) / 256, 256, 0, stream>>>(rowstart, blocksum);
    build_kernel<<<(NNZ_CNT + 255) / 256, 256, 0, stream>>>(
        adj_rows, adj_cols, adj_vals, rowstart, ticket, csr);

    const int spmm_blocks = (NTOT + 3) / 4;
    const size_t NE = (size_t)NTOT * EMB;

    // layer 0: src = concat(user,item) virtual -> ego to out_cl (cl == ego1); final = y/3
    spmm_perturb_kernel<true><<<spmm_blocks, 256, 0, stream>>>(
        nullptr, user_emb, item_emb, rowstart, csr, noise + 0 * NE,
        out_cl, out_final, /*store_ego=*/1, /*first_layer=*/1);
    // layer 1: src = out_cl -> ego to wsA; final += y/3
    spmm_perturb_kernel<false><<<spmm_blocks, 256, 0, stream>>>(
        out_cl, nullptr, nullptr, rowstart, csr, noise + 1 * NE,
        wsA, out_final, /*store_ego=*/1, /*first_layer=*/0);
    // layer 2: src = wsA -> ego not stored; final += y/3
    spmm_perturb_kernel<false><<<spmm_blocks, 256, 0, stream>>>(
        wsA, nullptr, nullptr, rowstart, csr, noise + 2 * NE,
        wsA, out_final, /*store_ego=*/0, /*first_layer=*/0);
}

// Round 4
// 454.712 us; speedup vs baseline: 7.3689x; 1.0847x over previous
//
#include <hip/hip_runtime.h>
#include <hip/hip_bf16.h>

#define EPSV 0.2f
#define USER_NUM 100000
#define ITEM_NUM 50000
#define NTOT 150000
#define NNZ_CNT 1200000
#define EMB 64

// ---- CSR build (3 kernels, no global scan) ----

// Pass 1: degree histogram + per-edge ticket (order within its row).
__global__ void hist_kernel(const int* __restrict__ rows,
                            int* __restrict__ hist,
                            int* __restrict__ ticket) {
    int e = blockIdx.x * blockDim.x + threadIdx.x;
    if (e < NNZ_CNT) ticket[e] = atomicAdd(&hist[rows[e]], 1);
}

// Pass 2: bump-allocate a contiguous slot range per row.
// Row order in the CSR pool is arbitrary (block-arrival order) — spmm only
// needs contiguity. One global atomic per 1024-thread block (147 total).
__global__ __launch_bounds__(1024) void alloc_kernel(const int* __restrict__ hist,
                                                     int2* __restrict__ rowrange,
                                                     int* __restrict__ cnt) {
    __shared__ int wsum[16];
    __shared__ int sbase;
    int t = threadIdx.x;
    int i = blockIdx.x * 1024 + t;
    int deg = (i < NTOT) ? hist[i] : 0;
    int lane = t & 63;
    int wid = t >> 6;
    // wave64 inclusive scan
    int inc = deg;
    #pragma unroll
    for (int off = 1; off < 64; off <<= 1) {
        int x = __shfl_up(inc, off, 64);
        if (lane >= off) inc += x;
    }
    if (lane == 63) wsum[wid] = inc;
    __syncthreads();
    if (t < 16) {
        int v = wsum[t];
        #pragma unroll
        for (int off = 1; off < 16; off <<= 1) {
            int x = __shfl_up(v, off, 64);
            if (t >= off) v += x;
        }
        wsum[t] = v;  // inclusive scan of wave sums
        if (t == 15) sbase = atomicAdd(cnt, v);
    }
    __syncthreads();
    int waveoff = (wid > 0) ? wsum[wid - 1] : 0;
    int excl = sbase + waveoff + inc - deg;
    if (i < NTOT) rowrange[i] = make_int2(excl, excl + deg);
}

// Pass 3: scatter edges into their slots (one 8B packed store per edge).
__global__ void build_kernel(const int* __restrict__ rows,
                             const int* __restrict__ cols,
                             const float* __restrict__ vals,
                             const int2* __restrict__ rowrange,
                             const int* __restrict__ ticket,
                             int2* __restrict__ csr) {
    int e = blockIdx.x * blockDim.x + threadIdx.x;
    if (e >= NNZ_CNT) return;
    int r = rows[e];
    int slot = rowrange[r].x + ticket[e];
    csr[slot] = make_int2(cols[e], __float_as_int(vals[e]));
}

// ---- Gather SpMM fused with perturbation / accumulation ----
// 4 rows per wave: lane = (rsub<<4)|q, q = float4 index within the 64-elem row.
// 8-edge batch per row -> 32 independent 256B gathers in flight per wave.
template <bool CONCAT>
__global__ void spmm_perturb_kernel(const float* __restrict__ src,
                                    const float* __restrict__ user_emb,
                                    const float* __restrict__ item_emb,
                                    const int2* __restrict__ rowrange,
                                    const int2* __restrict__ csr,
                                    const float* __restrict__ noise_k,
                                    float* __restrict__ ego_out,
                                    float* __restrict__ final_out,
                                    int store_ego, int first_layer) {
    int wid = threadIdx.x >> 6;        // wave in block: 0..3
    int lane = threadIdx.x & 63;
    int rsub = lane >> 4;              // 0..3 : row within wave
    int q = lane & 15;                 // float4 slot within row
    int row = blockIdx.x * 16 + wid * 4 + rsub;
    if (row >= NTOT) return;
    int2 rr = rowrange[row];
    int beg = rr.x, end = rr.y;
    size_t rowoff = (size_t)row * EMB;
    float4 nv = ((const float4*)(noise_k + rowoff))[q];  // issue early
    float4 acc = make_float4(0.f, 0.f, 0.f, 0.f);
    for (int j = beg; j < end; j += 8) {
        int cb[8];
        float vb[8];
        #pragma unroll
        for (int u = 0; u < 8; ++u) {
            int jj = j + u;
            int2 ee = csr[(jj < end) ? jj : beg];
            cb[u] = ee.x;
            vb[u] = (jj < end) ? __int_as_float(ee.y) : 0.f;
        }
        #pragma unroll
        for (int u = 0; u < 8; ++u) {
            int c = cb[u];
            const float* base;
            if (CONCAT)
                base = (c < USER_NUM) ? (user_emb + (size_t)c * EMB)
                                      : (item_emb + (size_t)(c - USER_NUM) * EMB);
            else
                base = src + (size_t)c * EMB;
            float4 x = ((const float4*)base)[q];
            acc.x = fmaf(vb[u], x.x, acc.x);
            acc.y = fmaf(vb[u], x.y, acc.y);
            acc.z = fmaf(vb[u], x.z, acc.z);
            acc.w = fmaf(vb[u], x.w, acc.w);
        }
    }
    // ||noise_row|| over the 16 lanes of this row group (xor 8,4,2,1 stays in-group)
    float s = nv.x * nv.x + nv.y * nv.y + nv.z * nv.z + nv.w * nv.w;
    #pragma unroll
    for (int off = 8; off > 0; off >>= 1) s += __shfl_xor(s, off, 64);
    float scale = EPSV / fmaxf(sqrtf(s), 1e-12f);
    auto pert = [&](float a, float n) {
        float sg = (a > 0.f) ? 1.f : ((a < 0.f) ? -1.f : 0.f);
        return fmaf(sg * scale, n, a);
    };
    float4 y = make_float4(pert(acc.x, nv.x), pert(acc.y, nv.y),
                           pert(acc.z, nv.z), pert(acc.w, nv.w));
    if (store_ego) ((float4*)(ego_out + rowoff))[q] = y;
    const float third = 1.f / 3.f;
    float4* fin4 = (float4*)(final_out + rowoff);
    if (first_layer) {
        fin4[q] = make_float4(y.x * third, y.y * third, y.z * third, y.w * third);
    } else {
        float4 o = fin4[q];
        fin4[q] = make_float4(o.x + y.x * third, o.y + y.y * third,
                              o.z + y.z * third, o.w + y.w * third);
    }
}

extern "C" void kernel_launch(void* const* d_in, const int* in_sizes, int n_in,
                              void* d_out, int out_size, void* d_ws, size_t ws_size,
                              hipStream_t stream) {
    const float* user_emb = (const float*)d_in[0];
    const float* item_emb = (const float*)d_in[1];
    const int*   adj_rows = (const int*)d_in[2];
    const int*   adj_cols = (const int*)d_in[3];
    const float* adj_vals = (const float*)d_in[4];
    const float* noise    = (const float*)d_in[5];

    float* out_final = (float*)d_out;                       // N x 64
    float* out_cl    = (float*)d_out + (size_t)NTOT * EMB;  // N x 64 (== ego after layer 0)

    // ws layout
    char* p = (char*)d_ws;
    float* wsA      = (float*)p;  p += (size_t)NTOT * EMB * sizeof(float); // 38.4 MB
    int2*  rowrange = (int2*)p;   p += (size_t)NTOT * sizeof(int2);        // 1.2 MB
    int2*  csr      = (int2*)p;   p += (size_t)NNZ_CNT * sizeof(int2);     // 9.6 MB
    int*   ticket   = (int*)p;    p += (size_t)NNZ_CNT * sizeof(int);      // 4.8 MB
    int*   hist     = (int*)p;    p += (size_t)NTOT * sizeof(int);         // 0.6 MB
    int*   cnt      = (int*)p;    p += 16 * sizeof(int);

    // zero hist + cnt in ONE memset (they're adjacent)
    hipMemsetAsync(hist, 0, ((size_t)NTOT + 16) * sizeof(int), stream);

    hist_kernel<<<(NNZ_CNT + 255) / 256, 256, 0, stream>>>(adj_rows, hist, ticket);
    alloc_kernel<<<(NTOT + 1023) / 1024, 1024, 0, stream>>>(hist, rowrange, cnt);
    build_kernel<<<(NNZ_CNT + 255) / 256, 256, 0, stream>>>(
        adj_rows, adj_cols, adj_vals, rowrange, ticket, csr);

    const int spmm_blocks = (NTOT + 15) / 16;
    const size_t NE = (size_t)NTOT * EMB;

    // layer 0: src = concat(user,item) virtual -> ego to out_cl (cl == ego1); final = y/3
    spmm_perturb_kernel<true><<<spmm_blocks, 256, 0, stream>>>(
        nullptr, user_emb, item_emb, rowrange, csr, noise + 0 * NE,
        out_cl, out_final, /*store_ego=*/1, /*first_layer=*/1);
    // layer 1: src = out_cl -> ego to wsA; final += y/3
    spmm_perturb_kernel<false><<<spmm_blocks, 256, 0, stream>>>(
        out_cl, nullptr, nullptr, rowrange, csr, noise + 1 * NE,
        wsA, out_final, /*store_ego=*/1, /*first_layer=*/0);
    // layer 2: src = wsA -> ego not stored; final += y/3
    spmm_perturb_kernel<false><<<spmm_blocks, 256, 0, stream>>>(
        wsA, nullptr, nullptr, rowrange, csr, noise + 2 * NE,
        wsA, out_final, /*store_ego=*/0, /*first_layer=*/0);
}